// Round 7
// baseline (6168.676 us; speedup 1.0000x reference)
//
#include <hip/hip_runtime.h>
#include <hip/hip_bf16.h>
#include <hip/hip_fp16.h>

// ---------------------------------------------------------------------------
// 4-layer LSTM (H=1024, B=64, T=256) + FC, persistent pipelined kernel.
// R7 = R6 structure with 2 WGs per CU (512 WGs total, 128 per layer, 8 hidden
//      units per WG, 73728 B LDS per WG). Co-resident phase-shifted layers on
//      each CU hide the handoff latency chain. K-partition of the reduce
//      partials unchanged -> absmax should be bit-identical to R4/R6.
// - fresh-address h ring (write-once slots): consumers PLAIN cached loads
//   (per-XCD L2 sharing), producers sc write-through; one-time agent-acquire
//   fence kills stale lines across graph replays.
// - per-WG epoch flags (no RMW fan-in); fallback counter path if ws small.
// ---------------------------------------------------------------------------

#define H      1024
#define BATCH  64
#define T      256
#define RINGN  8
#define WPL    128                                   // WGs per layer
#define UPW    8                                     // hidden units per WG

typedef _Float16 f16x8 __attribute__((ext_vector_type(8)));
typedef _Float16 f16x4 __attribute__((ext_vector_type(4)));
typedef float    f32x4 __attribute__((ext_vector_type(4)));

// ws layout (bytes)
#define WPACK_HH_SZ  (4ull*WPL*32*2*64*8*2)          // 33554432: [l][wg][ks][nt][lane][8] f16
#define WPACK_IH_SZ  (3ull*WPL*32*2*64*8*2)          // 25165824
#define HRING_OFF    (WPACK_HH_SZ + WPACK_IH_SZ)     // 58720256
#define SLOT_ELEMS   65536                           // per (l,slot): 64 batch x 1024 units f16
#define SLOT_BYTES   131072ull
#define CNT_INTS     (4*257*16)                      // fallback counter flags (64B-padded)
#define CNT_BYTES    ((unsigned long long)CNT_INTS*4)
#define EFLAG_INTS   (4*WPL)                         // fresh-mode epoch flags [l][wg]
#define EFLAG_BYTES  ((unsigned long long)EFLAG_INTS*4)

__host__ __device__ __forceinline__ unsigned long long ring_bytes(int nslot) {
  return 4ull*(unsigned)nslot*SLOT_BYTES;
}
__device__ __forceinline__ int cidx(int l, int s) { return (l*257 + s)*16; }

// fresh mode: bit-reversed slot index kills any sequential-prefetch adjacency
__device__ __forceinline__ int aslot(int s, int fresh) {
  if (!fresh) return s & 7;
  return (s >= 256) ? 256 : (int)(__brev((unsigned)s) >> 24);
}

__device__ __forceinline__ void wait_eq(int* p, int target) {
  int it = 0;
  while (__hip_atomic_load(p, __ATOMIC_RELAXED, __HIP_MEMORY_SCOPE_AGENT) < target) {
    __builtin_amdgcn_s_sleep(1);
    if (++it > 20000000) break;   // failsafe: never hang the harness
  }
}

// whole-wave epoch poll over 128 words: lane i watches ef[i] and ef[i+64]
__device__ __forceinline__ void wait_epoch(const int* ef, int lane, int need) {
  int it = 0;
  for (;;) {
    int v0 = __hip_atomic_load(ef + lane,      __ATOMIC_RELAXED, __HIP_MEMORY_SCOPE_AGENT);
    int v1 = __hip_atomic_load(ef + lane + 64, __ATOMIC_RELAXED, __HIP_MEMORY_SCOPE_AGENT);
    if (__all(v0 >= need && v1 >= need)) break;
    __builtin_amdgcn_s_sleep(1);
    if (++it > 20000000) break;   // failsafe
  }
}

__device__ __forceinline__ f16x8 load_h8_sc(const _Float16* p) {
  const unsigned long long* q = (const unsigned long long*)p;
  unsigned long long lo = __hip_atomic_load(q,     __ATOMIC_RELAXED, __HIP_MEMORY_SCOPE_AGENT);
  unsigned long long hi = __hip_atomic_load(q + 1, __ATOMIC_RELAXED, __HIP_MEMORY_SCOPE_AGENT);
  union { unsigned long long u[2]; f16x8 v; } c;
  c.u[0] = lo; c.u[1] = hi;
  return c.v;
}

// --- pack weights fp32 -> fp16 MFMA-fragment layout; zero h ring slot 0
// B-tile per WG: 32 gate rows as 2 n-tiles; within-tile col c (=lane&15) maps
// to global row (nt*2 + (c>>3))*1024 + wg*8 + (c&7).
__global__ void pack_kernel(const float* __restrict__ w_ih_rest,
                            const float* __restrict__ w_hh,
                            char* __restrict__ ws, int nslot)
{
  const long long NS_HH = 4ll*WPL*32*2*64;  // 2097152
  const long long NS_IH = 3ll*WPL*32*2*64;  // 1572864
  const long long NS_HZ = 4ll*8192;         // uint4 slots to zero slot-0 of each layer ring
  const long long NTOT  = NS_HH + NS_IH + NS_HZ + 4;
  _Float16* whh_dst = (_Float16*)ws;
  _Float16* wih_dst = (_Float16*)(ws + WPACK_HH_SZ);
  int* cnt = (int*)(ws + HRING_OFF + ring_bytes(nslot));
  for (long long i = blockIdx.x*(long long)blockDim.x + threadIdx.x; i < NTOT;
       i += (long long)gridDim.x*blockDim.x) {
    if (i < NS_HH + NS_IH) {
      const bool is_hh = (i < NS_HH);
      long long slot = is_hh ? i : (i - NS_HH);
      long long j = slot;
      int lane = (int)(j & 63);  j >>= 6;
      int nt   = (int)(j & 1);   j >>= 1;
      int ks   = (int)(j & 31);  j >>= 5;
      int wg   = (int)(j & 127); j >>= 7;
      int l    = (int)j;
      int c    = lane & 15;
      int row  = (nt*2 + (c >> 3))*1024 + wg*UPW + (c & 7);  // global gate row
      int col  = ks*32 + (lane >> 4)*8;
      const float* src = (is_hh ? w_hh : w_ih_rest) + ((long long)l*4096 + row)*1024 + col;
      f16x8 v;
      #pragma unroll
      for (int e = 0; e < 8; e++) v[e] = (_Float16)src[e];
      *(f16x8*)((is_hh ? whh_dst : wih_dst) + slot*8) = v;
    } else if (i < NS_HH + NS_IH + NS_HZ) {
      long long j = i - (NS_HH + NS_IH);
      long long l = j >> 13;            // /8192
      long long off = j & 8191;
      uint4 z = make_uint4(0,0,0,0);
      ((uint4*)(ws + HRING_OFF))[(l*(long long)nslot)*8192 + off] = z;  // zero h[l][slot0]
    } else {
      int l = (int)(i - (NS_HH + NS_IH + NS_HZ));
      cnt[cidx(l,0)] = WPL;                     // fallback-mode initial "produced"
    }
  }
}

__global__ __launch_bounds__(256, 2) void lstm_main(
    const float* __restrict__ x,
    const float* __restrict__ wih0,
    const float* __restrict__ bih,
    const float* __restrict__ bhh,
    char* __restrict__ ws, int nslot, int fresh)
{
  // one-time agent acquire: invalidates stale L1/L2 lines from prior replays.
  __builtin_amdgcn_fence(__ATOMIC_ACQUIRE, "agent");

  extern __shared__ char lds[];
  _Float16* whh_lds = (_Float16*)lds;              // 65536 B, frag layout [ks][nt][lane][8]
  _Float16* buf0    = (_Float16*)(lds + 65536);    // 4096 B partial-sum frags (waves 0+2)
  _Float16* buf1    = (_Float16*)(lds + 69632);    // 4096 B partial-sum frags (waves 1+3)

  const int l   = blockIdx.x >> 7;
  const int wg  = blockIdx.x & 127;
  const int tid = threadIdx.x;
  const int wave = tid >> 6;
  const int lane = tid & 63;

  const _Float16* wpack_hh = (const _Float16*)ws + (size_t)(l*WPL + wg)*32768;
  const _Float16* wpack_ih = (l > 0)
      ? (const _Float16*)(ws + WPACK_HH_SZ) + (size_t)((l-1)*WPL + wg)*32768
      : wpack_hh;  // unused for l==0
  _Float16* hring = (_Float16*)(ws + HRING_OFF);
  int* cnt    = (int*)(ws + HRING_OFF + ring_bytes(nslot));
  int* cnt2   = cnt + CNT_INTS;
  int* eflags = cnt2 + CNT_INTS;                   // [l][wg] epoch words (fresh mode)

  // stage w_hh slice into LDS (one-time; wpack is immutable during this kernel)
  {
    const uint4* src = (const uint4*)wpack_hh;
    uint4* dst = (uint4*)whh_lds;
    for (int i = tid; i < 4096; i += 256) dst[i] = src[i];
  }

  // elementwise ownership: thread -> (batch b_ew, 2 hidden units u0..u0+1)
  const int b_ew = tid >> 2;
  const int u0   = (tid & 3) * 2;
  float cst[2] = {0.f, 0.f};
  float bias[2][4];            // [item][gate]
  float wx0[2][4], wx1[2][4];  // layer-0 input weights (K=2 handled in VALU)
  #pragma unroll
  for (int ii = 0; ii < 2; ii++) {
    #pragma unroll
    for (int g = 0; g < 4; g++) {
      int row = g*1024 + wg*UPW + u0 + ii;
      bias[ii][g] = bih[l*4096 + row] + bhh[l*4096 + row];
      if (l == 0) { wx0[ii][g] = wih0[row*2]; wx1[ii][g] = wih0[row*2 + 1]; }
      else        { wx0[ii][g] = 0.f;         wx1[ii][g] = 0.f; }
    }
  }
  __syncthreads();

  const int m_row = lane & 15, quad = lane >> 4;

  for (int s = 1; s <= T; s++) {
    // hoist layer-0 x loads: independent of all flags, issue before the spin
    float xs0 = 0.f, xs1 = 0.f;
    if (l == 0) {
      xs0 = x[((size_t)b_ew*T + (s-1))*2];
      xs1 = x[((size_t)b_ew*T + (s-1))*2 + 1];
    }

    if (fresh) {
      // wave-parallel epoch polls: no RMW, two 64-lane sc loads per poll
      if (wave == 0)               wait_epoch(eflags + l*WPL,     lane, s-1);
      else if (wave == 1 && l > 0) wait_epoch(eflags + (l-1)*WPL, lane, s);
    } else {
      if (tid == 0)          wait_eq(&cnt[cidx(l, s-1)], WPL);
      else if (tid == 64)  { if (l > 0) wait_eq(&cnt[cidx(l-1, s)], WPL); }
      else if (tid == 128) { if (l < 3 && s > RINGN) wait_eq(&cnt2[cidx(l, s-RINGN)], WPL); }
    }
    __syncthreads();

    // A source: for l>0 waves 0-1 consume h_below[s] (with w_ih), waves 2-3 h_own[s-1] (w_hh)
    const _Float16* asrc = (l > 0 && wave < 2)
        ? hring + ((size_t)(l-1)*nslot + aslot(s,   fresh))*SLOT_ELEMS
        : hring + ((size_t)l*nslot     + aslot(s-1, fresh))*SLOT_ELEMS;

    f32x4 acc[4][2];
    #pragma unroll
    for (int mt = 0; mt < 4; mt++)
      #pragma unroll
      for (int nt = 0; nt < 2; nt++) acc[mt][nt] = (f32x4){0.f, 0.f, 0.f, 0.f};

    auto kbody = [&](int ks, bool from_lds, bool plain) {
      const int kb = ks*32 + quad*8;
      f16x8 a[4], bb[2];
      #pragma unroll
      for (int mt = 0; mt < 4; mt++) {
        const _Float16* ap = asrc + (size_t)(mt*16 + m_row)*1024 + kb;
        a[mt] = plain ? *(const f16x8*)ap : load_h8_sc(ap);
      }
      if (from_lds) {
        #pragma unroll
        for (int nt = 0; nt < 2; nt++)
          bb[nt] = *(const f16x8*)(whh_lds + ((ks*2 + nt)*64 + lane)*8);
      } else {
        #pragma unroll
        for (int nt = 0; nt < 2; nt++)
          bb[nt] = *(const f16x8*)(wpack_ih + ((size_t)(ks*2 + nt)*64 + lane)*8);
      }
      #pragma unroll
      for (int mt = 0; mt < 4; mt++)
        #pragma unroll
        for (int nt = 0; nt < 2; nt++)
          acc[mt][nt] = __builtin_amdgcn_mfma_f32_16x16x32_f16(a[mt], bb[nt], acc[mt][nt], 0, 0, 0);
    };

    if (fresh) {
      if (l == 0) {
        #pragma unroll 2
        for (int i = 0; i < 8; i++) kbody(wave*8 + i, true, true);
      } else if (wave < 2) {
        #pragma unroll 2
        for (int i = 0; i < 16; i++) kbody(wave*16 + i, false, true);
      } else {
        #pragma unroll 2
        for (int i = 0; i < 16; i++) kbody((wave-2)*16 + i, true, true);
      }
    } else {
      if (l == 0) {
        #pragma unroll 2
        for (int i = 0; i < 8; i++) kbody(wave*8 + i, true, false);
      } else if (wave < 2) {
        #pragma unroll 2
        for (int i = 0; i < 16; i++) kbody(wave*16 + i, false, false);
      } else {
        #pragma unroll 2
        for (int i = 0; i < 16; i++) kbody((wave-2)*16 + i, true, false);
      }
    }

    // combine 4 wave-partials -> buf0 (w0+w2), buf1 (w1+w3), fp16 frags
    _Float16* mybuf = ((wave & 1) == 0) ? buf0 : buf1;
    if (wave >= 2) {
      #pragma unroll
      for (int mt = 0; mt < 4; mt++)
        #pragma unroll
        for (int nt = 0; nt < 2; nt++) {
          f16x4 v;
          #pragma unroll
          for (int e = 0; e < 4; e++) v[e] = (_Float16)acc[mt][nt][e];
          *(f16x4*)(mybuf + ((mt*2 + nt)*64 + lane)*4) = v;
        }
    }
    __syncthreads();   // drains vmcnt: all h reads physically complete
    if (wave < 2) {
      #pragma unroll
      for (int mt = 0; mt < 4; mt++)
        #pragma unroll
        for (int nt = 0; nt < 2; nt++) {
          f16x4 p = *(f16x4*)(mybuf + ((mt*2 + nt)*64 + lane)*4);
          f16x4 v;
          #pragma unroll
          for (int e = 0; e < 4; e++) v[e] = (_Float16)(acc[mt][nt][e] + (float)p[e]);
          *(f16x4*)(mybuf + ((mt*2 + nt)*64 + lane)*4) = v;
        }
    }
    // ring backpressure signal only needed when slots are reused (fallback mode)
    if (!fresh && tid == 0 && l > 0)
      __hip_atomic_fetch_add(&cnt2[cidx(l-1, s)], 1, __ATOMIC_RELAXED, __HIP_MEMORY_SCOPE_AGENT);
    __syncthreads();

    // elementwise gates -> c,h  (fp32)
    {
      const int mt = b_ew >> 4, q = (b_ew & 15) >> 2, reg = b_ew & 3;
      union { _Float16 h[2]; unsigned u; } hv;
      #pragma unroll
      for (int ii = 0; ii < 2; ii++) {
        const int u = u0 + ii;
        float pre[4];
        #pragma unroll
        for (int g = 0; g < 4; g++) {
          int idx = ((mt*2 + (g >> 1))*64 + (16*q + (g & 1)*8 + u))*4 + reg;
          pre[g] = (float)buf0[idx] + (float)buf1[idx] + bias[ii][g]
                 + wx0[ii][g]*xs0 + wx1[ii][g]*xs1;
        }
        float ig = 1.f/(1.f + __expf(-pre[0]));
        float fg = 1.f/(1.f + __expf(-pre[1]));
        float gg = 2.f/(1.f + __expf(-2.f*pre[2])) - 1.f;
        float og = 1.f/(1.f + __expf(-pre[3]));
        float c  = fg*cst[ii] + ig*gg;
        cst[ii] = c;
        float th = 2.f/(1.f + __expf(-2.f*c)) - 1.f;
        hv.h[ii] = (_Float16)(og*th);
      }
      _Float16* hdst = hring + ((size_t)l*nslot + aslot(s, fresh))*SLOT_ELEMS
                     + (size_t)b_ew*1024 + wg*UPW + u0;
      // sc write-through: coherence point holds the authoritative copy
      __hip_atomic_store((unsigned*)hdst, hv.u, __ATOMIC_RELAXED, __HIP_MEMORY_SCOPE_AGENT);
    }
    __syncthreads();   // drains vmcnt: h stores acked at coherence point before flag
    if (tid == 0) {
      if (fresh)
        __hip_atomic_store(&eflags[l*WPL + wg], s, __ATOMIC_RELAXED, __HIP_MEMORY_SCOPE_AGENT);
      else
        __hip_atomic_fetch_add(&cnt[cidx(l, s)], 1, __ATOMIC_RELAXED, __HIP_MEMORY_SCOPE_AGENT);
    }
  }
}

__global__ void fc_kernel(const char* __restrict__ ws,
                          const float* __restrict__ fcw,
                          const float* __restrict__ fcb,
                          float* __restrict__ out, int nslot, int fresh)
{
  const _Float16* h3 = (const _Float16*)(ws + HRING_OFF)
                     + ((size_t)3*nslot + aslot(T, fresh))*SLOT_ELEMS;  // layer 3, t=256
  __shared__ float red[256];
  const int tid = threadIdx.x;
  const int b = tid >> 2, p = tid & 3;
  float sum = 0.f;
  for (int j = p*256; j < p*256 + 256; j++)
    sum += fcw[j] * (float)h3[(size_t)b*1024 + j];
  red[tid] = sum;
  __syncthreads();
  if (p == 0)
    out[b] = red[tid] + red[tid+1] + red[tid+2] + red[tid+3] + fcb[0];
}

extern "C" void kernel_launch(void* const* d_in, const int* in_sizes, int n_in,
                              void* d_out, int out_size, void* d_ws, size_t ws_size,
                              hipStream_t stream)
{
  const float* x    = (const float*)d_in[0];
  const float* wih0 = (const float*)d_in[1];
  const float* wihr = (const float*)d_in[2];
  const float* whh  = (const float*)d_in[3];
  const float* bih  = (const float*)d_in[4];
  const float* bhh  = (const float*)d_in[5];
  const float* fcw  = (const float*)d_in[6];
  const float* fcb  = (const float*)d_in[7];
  float* out = (float*)d_out;
  char* ws = (char*)d_ws;
  (void)in_sizes; (void)n_in; (void)out_size;

  const unsigned long long ws_big   = HRING_OFF + ring_bytes(257) + 2*CNT_BYTES + EFLAG_BYTES;
  const unsigned long long ws_small = HRING_OFF + ring_bytes(8)   + 2*CNT_BYTES + EFLAG_BYTES;
  if (ws_size < ws_small) return;
  const int fresh = (ws_size >= ws_big) ? 1 : 0;
  const int nslot = fresh ? 257 : 8;

  // opt-in to 73728 B dynamic LDS (host-side, idempotent, capture-safe)
  hipFuncSetAttribute(reinterpret_cast<const void*>(lstm_main),
                      hipFuncAttributeMaxDynamicSharedMemorySize, 73728);

  // zero counters + epoch flags (epoch 0 == "initial h (zeros) produced")
  hipMemsetAsync(ws + HRING_OFF + ring_bytes(nslot), 0,
                 (size_t)(2*CNT_BYTES + EFLAG_BYTES), stream);
  pack_kernel<<<512, 256, 0, stream>>>(wihr, whh, ws, nslot);
  lstm_main<<<512, 256, 73728, stream>>>(x, wih0, bih, bhh, ws, nslot, fresh);
  fc_kernel<<<1, 256, 0, stream>>>(ws, fcw, fcb, out, nslot, fresh);
}

// Round 8
// 5425.078 us; speedup vs baseline: 1.1371x; 1.1371x over previous
//
#include <hip/hip_runtime.h>
#include <hip/hip_bf16.h>
#include <hip/hip_fp16.h>

// ---------------------------------------------------------------------------
// 4-layer LSTM (H=1024, B=64, T=256) + FC, persistent pipelined kernel.
// R8 = R4 topology (256 WGs, 1/CU, 4 waves, counter flags, fresh h ring,
//      sc h-stores + plain L2 consumer loads) with the step SPLIT in two:
//   phase B: xp[s] = h_{l-1}[s] @ w_ih  -- w_ih REGISTER-resident (128 VGPR),
//            result folded into an 8 KB LDS buffer (serial wave chain).
//   phase A: h_l[s] from h_l[s-1] @ w_hh (LDS-resident, K=1024) + xp + bias.
// This removes the per-step 25 MB w_ih L2/IF$ stream (R4's FETCH evidence)
// and halves the critical-path K. l==0 keeps the trivial VALU x-projection.
// ---------------------------------------------------------------------------

#define H      1024
#define BATCH  64
#define T      256
#define NSLOT  257

typedef _Float16 f16x8 __attribute__((ext_vector_type(8)));
typedef _Float16 f16x4 __attribute__((ext_vector_type(4)));
typedef float    f32x4 __attribute__((ext_vector_type(4)));

// ws layout (bytes)
#define WPACK_HH_SZ  (4ull*64*32*4*64*8*2)           // 33554432: [l][wg][ks][nt][lane][8] f16
#define WPACK_IH_SZ  (3ull*64*32*4*64*8*2)           // 25165824
#define HRING_OFF    (WPACK_HH_SZ + WPACK_IH_SZ)     // 58720256
#define SLOT_ELEMS   65536                           // per (l,slot): 64 batch x 1024 units f16
#define SLOT_BYTES   131072ull
#define HRING_SZ     (4ull*NSLOT*SLOT_BYTES)
#define CNT_OFF      (HRING_OFF + HRING_SZ)
#define CNT_INTS     (4*257*16)                      // counter flags, 64B-padded entries
#define CNT_BYTES    ((unsigned long long)CNT_INTS*4)
#define WS_NEEDED    (CNT_OFF + CNT_BYTES)

// LDS offsets (dynamic, 155648 B total)
#define LDS_WHH   0
#define LDS_BUF0  131072
#define LDS_BUF1  139264
#define LDS_XP    147456
#define LDS_TOTAL 155648

__device__ __forceinline__ int cidx(int l, int s) { return (l*257 + s)*16; }

// fresh slot: bit-reversed step index (write-once addresses within a launch)
__device__ __forceinline__ int aslot(int s) {
  return (s >= 256) ? 256 : (int)(__brev((unsigned)s) >> 24);
}

__device__ __forceinline__ void wait_eq64(int* p) {
  int it = 0;
  while (__hip_atomic_load(p, __ATOMIC_RELAXED, __HIP_MEMORY_SCOPE_AGENT) < 64) {
    __builtin_amdgcn_s_sleep(1);
    if (++it > 50000000) break;   // failsafe: never hang the harness
  }
}

// --- pack weights fp32 -> fp16 MFMA-fragment layout; zero h slot 0; preset cnt[l][0]=64
__global__ void pack_kernel(const float* __restrict__ w_ih_rest,
                            const float* __restrict__ w_hh,
                            char* __restrict__ ws)
{
  const long long NS_HH = 4ll*64*32*4*64;   // 2097152
  const long long NS_IH = 3ll*64*32*4*64;   // 1572864
  const long long NS_HZ = 4ll*8192;         // uint4 slots to zero slot-0 of each layer ring
  const long long NTOT  = NS_HH + NS_IH + NS_HZ + 4;
  _Float16* whh_dst = (_Float16*)ws;
  _Float16* wih_dst = (_Float16*)(ws + WPACK_HH_SZ);
  int* cnt = (int*)(ws + CNT_OFF);
  for (long long i = blockIdx.x*(long long)blockDim.x + threadIdx.x; i < NTOT;
       i += (long long)gridDim.x*blockDim.x) {
    if (i < NS_HH + NS_IH) {
      const bool is_hh = (i < NS_HH);
      long long slot = is_hh ? i : (i - NS_HH);
      long long j = slot;
      int lane = (int)(j & 63); j >>= 6;
      int nt   = (int)(j & 3);  j >>= 2;
      int ks   = (int)(j & 31); j >>= 5;
      int wg   = (int)(j & 63); j >>= 6;
      int l    = (int)j;
      int row = nt*1024 + wg*16 + (lane & 15);      // global gate row (nt = gate: i,f,g,o)
      int col = ks*32 + (lane >> 4)*8;
      const float* src = (is_hh ? w_hh : w_ih_rest) + ((long long)l*4096 + row)*1024 + col;
      f16x8 v;
      #pragma unroll
      for (int e = 0; e < 8; e++) v[e] = (_Float16)src[e];
      *(f16x8*)((is_hh ? whh_dst : wih_dst) + slot*8) = v;
    } else if (i < NS_HH + NS_IH + NS_HZ) {
      long long j = i - (NS_HH + NS_IH);
      long long l = j >> 13;            // /8192
      long long off = j & 8191;
      uint4 z = make_uint4(0,0,0,0);
      ((uint4*)(ws + HRING_OFF))[(l*(long long)NSLOT)*8192 + off] = z;  // zero h[l][slot0]
    } else {
      int l = (int)(i - (NS_HH + NS_IH + NS_HZ));
      cnt[cidx(l,0)] = 64;                                  // initial state "produced"
    }
  }
}

__global__ __launch_bounds__(256, 1) void lstm_main(
    const float* __restrict__ x,
    const float* __restrict__ wih0,
    const float* __restrict__ bih,
    const float* __restrict__ bhh,
    char* __restrict__ ws)
{
  // one-time agent acquire: invalidates stale L1/L2 lines from prior replays.
  __builtin_amdgcn_fence(__ATOMIC_ACQUIRE, "agent");

  extern __shared__ char lds[];
  _Float16* whh_lds = (_Float16*)(lds + LDS_WHH);    // 131072 B [ks][nt][lane][8]
  _Float16* buf0    = (_Float16*)(lds + LDS_BUF0);   // 8192 B partial frags (w0+w2)
  _Float16* buf1    = (_Float16*)(lds + LDS_BUF1);   // 8192 B partial frags (w1+w3)
  _Float16* xp_lds  = (_Float16*)(lds + LDS_XP);     // 8192 B xp frags (phase B result)

  const int l   = blockIdx.x >> 6;
  const int wg  = blockIdx.x & 63;
  const int tid = threadIdx.x;
  const int wave = tid >> 6;
  const int lane = tid & 63;

  const _Float16* wpack_hh = (const _Float16*)ws + (size_t)(l*64 + wg)*65536;
  _Float16* hring = (_Float16*)(ws + HRING_OFF);
  int* cnt = (int*)(ws + CNT_OFF);

  // stage w_hh slice into LDS (one-time)
  {
    const uint4* src = (const uint4*)wpack_hh;
    uint4* dst = (uint4*)whh_lds;
    for (int i = tid; i < 8192; i += 256) dst[i] = src[i];
  }

  // w_ih slice REGISTER-resident (l>0): wave w holds ks = w*8 .. w*8+7
  f16x8 breg[8][4];
  if (l > 0) {
    const _Float16* wih = (const _Float16*)(ws + WPACK_HH_SZ) + (size_t)((l-1)*64 + wg)*65536;
    #pragma unroll
    for (int i = 0; i < 8; i++)
      #pragma unroll
      for (int nt = 0; nt < 4; nt++)
        breg[i][nt] = *(const f16x8*)(wih + (((size_t)(wave*8 + i)*4 + nt)*64 + lane)*8);
  }

  // elementwise ownership: thread -> (batch b_ew, 4 hidden units u0..u0+3)
  const int b_ew = tid >> 2;
  const int u0   = (tid & 3) * 4;
  float cst[4] = {0.f, 0.f, 0.f, 0.f};
  float bias[4][4];
  float wx0[4][4], wx1[4][4];
  #pragma unroll
  for (int ii = 0; ii < 4; ii++) {
    #pragma unroll
    for (int g = 0; g < 4; g++) {
      int row = g*1024 + wg*16 + u0 + ii;
      bias[ii][g] = bih[l*4096 + row] + bhh[l*4096 + row];
      if (l == 0) { wx0[ii][g] = wih0[row*2]; wx1[ii][g] = wih0[row*2 + 1]; }
      else        { wx0[ii][g] = 0.f;         wx1[ii][g] = 0.f; }
    }
  }
  __syncthreads();

  const int m_row = lane & 15, quad = lane >> 4;

  for (int s = 1; s <= T; s++) {
    // hoist layer-0 x loads
    float xs0 = 0.f, xs1 = 0.f;
    if (l == 0) {
      xs0 = x[((size_t)b_ew*T + (s-1))*2];
      xs1 = x[((size_t)b_ew*T + (s-1))*2 + 1];
    }

    // ---------------- phase B: xp[s] = h_{l-1}[s] @ w_ih (l>0) ----------------
    if (l > 0) {
      if (tid == 0) wait_eq64(&cnt[cidx(l-1, s)]);
      __syncthreads();
      const _Float16* asrcB = hring + ((size_t)(l-1)*NSLOT + aslot(s))*SLOT_ELEMS;

      f32x4 acc[4][4];
      #pragma unroll
      for (int mt = 0; mt < 4; mt++)
        #pragma unroll
        for (int nt = 0; nt < 4; nt++) acc[mt][nt] = (f32x4){0.f,0.f,0.f,0.f};

      #pragma unroll 2
      for (int i = 0; i < 8; i++) {
        const int kb = (wave*8 + i)*32 + quad*8;
        f16x8 a[4];
        #pragma unroll
        for (int mt = 0; mt < 4; mt++)
          a[mt] = *(const f16x8*)(asrcB + (size_t)(mt*16 + m_row)*1024 + kb);
        #pragma unroll
        for (int mt = 0; mt < 4; mt++)
          #pragma unroll
          for (int nt = 0; nt < 4; nt++)
            acc[mt][nt] = __builtin_amdgcn_mfma_f32_16x16x32_f16(a[mt], breg[i][nt], acc[mt][nt], 0, 0, 0);
      }

      // serial wave-chain fold into xp_lds (f16): w3 -> w2 -> w1 -> w0
      #pragma unroll
      for (int w = 3; w >= 0; w--) {
        if (wave == w) {
          #pragma unroll
          for (int mt = 0; mt < 4; mt++)
            #pragma unroll
            for (int nt = 0; nt < 4; nt++) {
              _Float16* p = xp_lds + ((mt*4 + nt)*64 + lane)*4;
              f16x4 prev;
              if (w < 3) prev = *(f16x4*)p;
              f16x4 v;
              #pragma unroll
              for (int e = 0; e < 4; e++)
                v[e] = (_Float16)(acc[mt][nt][e] + (w < 3 ? (float)prev[e] : 0.f));
              *(f16x4*)p = v;
            }
        }
        __syncthreads();
      }
    }

    // ---------------- phase A: h_l[s] from h_l[s-1] @ w_hh ----------------
    if (tid == 0) wait_eq64(&cnt[cidx(l, s-1)]);
    __syncthreads();
    const _Float16* asrcA = hring + ((size_t)l*NSLOT + aslot(s-1))*SLOT_ELEMS;

    f32x4 acc[4][4];
    #pragma unroll
    for (int mt = 0; mt < 4; mt++)
      #pragma unroll
      for (int nt = 0; nt < 4; nt++) acc[mt][nt] = (f32x4){0.f,0.f,0.f,0.f};

    #pragma unroll 2
    for (int i = 0; i < 8; i++) {
      const int ks = wave*8 + i;
      const int kb = ks*32 + quad*8;
      f16x8 a[4], bb[4];
      #pragma unroll
      for (int mt = 0; mt < 4; mt++)
        a[mt] = *(const f16x8*)(asrcA + (size_t)(mt*16 + m_row)*1024 + kb);
      #pragma unroll
      for (int nt = 0; nt < 4; nt++)
        bb[nt] = *(const f16x8*)(whh_lds + ((ks*4 + nt)*64 + lane)*8);
      #pragma unroll
      for (int mt = 0; mt < 4; mt++)
        #pragma unroll
        for (int nt = 0; nt < 4; nt++)
          acc[mt][nt] = __builtin_amdgcn_mfma_f32_16x16x32_f16(a[mt], bb[nt], acc[mt][nt], 0, 0, 0);
    }

    // two-stage reduce (R4-proven): w2->buf0, w3->buf1; then w0+=buf0, w1+=buf1
    _Float16* mybuf = ((wave & 1) == 0) ? buf0 : buf1;
    if (wave >= 2) {
      #pragma unroll
      for (int mt = 0; mt < 4; mt++)
        #pragma unroll
        for (int nt = 0; nt < 4; nt++) {
          f16x4 v;
          #pragma unroll
          for (int e = 0; e < 4; e++) v[e] = (_Float16)acc[mt][nt][e];
          *(f16x4*)(mybuf + ((mt*4 + nt)*64 + lane)*4) = v;
        }
    }
    __syncthreads();
    if (wave < 2) {
      #pragma unroll
      for (int mt = 0; mt < 4; mt++)
        #pragma unroll
        for (int nt = 0; nt < 4; nt++) {
          f16x4 p = *(f16x4*)(mybuf + ((mt*4 + nt)*64 + lane)*4);
          f16x4 v;
          #pragma unroll
          for (int e = 0; e < 4; e++) v[e] = (_Float16)(acc[mt][nt][e] + (float)p[e]);
          *(f16x4*)(mybuf + ((mt*4 + nt)*64 + lane)*4) = v;
        }
    }
    __syncthreads();

    // gates -> c,h (fp32); xp from LDS (l>0) or VALU x-proj (l==0)
    {
      const int mt = b_ew >> 4, q = (b_ew & 15) >> 2, reg = b_ew & 3;
      f16x4 hv;
      #pragma unroll
      for (int ii = 0; ii < 4; ii++) {
        const int u = u0 + ii;
        float pre[4];
        #pragma unroll
        for (int g = 0; g < 4; g++) {
          int idx = ((mt*4 + g)*64 + (u + 16*q))*4 + reg;
          float xp = (l == 0) ? (wx0[ii][g]*xs0 + wx1[ii][g]*xs1)
                              : (float)xp_lds[idx];
          pre[g] = (float)buf0[idx] + (float)buf1[idx] + bias[ii][g] + xp;
        }
        float ig = 1.f/(1.f + __expf(-pre[0]));
        float fg = 1.f/(1.f + __expf(-pre[1]));
        float gg = 2.f/(1.f + __expf(-2.f*pre[2])) - 1.f;
        float og = 1.f/(1.f + __expf(-pre[3]));
        float c  = fg*cst[ii] + ig*gg;
        cst[ii] = c;
        float th = 2.f/(1.f + __expf(-2.f*c)) - 1.f;
        hv[ii] = (_Float16)(og*th);
      }
      _Float16* hdst = hring + ((size_t)l*NSLOT + aslot(s))*SLOT_ELEMS
                     + (size_t)b_ew*1024 + wg*16 + u0;
      union { f16x4 v; unsigned long long u; } cv; cv.v = hv;
      // sc write-through: coherence point holds the authoritative copy
      __hip_atomic_store((unsigned long long*)hdst, cv.u,
                         __ATOMIC_RELAXED, __HIP_MEMORY_SCOPE_AGENT);
    }
    __syncthreads();   // drains vmcnt: h stores acked before flag
    if (tid == 0)
      __hip_atomic_fetch_add(&cnt[cidx(l, s)], 1, __ATOMIC_RELAXED, __HIP_MEMORY_SCOPE_AGENT);
  }
}

__global__ void fc_kernel(const char* __restrict__ ws,
                          const float* __restrict__ fcw,
                          const float* __restrict__ fcb,
                          float* __restrict__ out)
{
  const _Float16* h3 = (const _Float16*)(ws + HRING_OFF)
                     + ((size_t)3*NSLOT + 256)*SLOT_ELEMS;   // layer 3, slot of t=256
  __shared__ float red[256];
  const int tid = threadIdx.x;
  const int b = tid >> 2, p = tid & 3;
  float sum = 0.f;
  for (int j = p*256; j < p*256 + 256; j++)
    sum += fcw[j] * (float)h3[(size_t)b*1024 + j];
  red[tid] = sum;
  __syncthreads();
  if (p == 0)
    out[b] = red[tid] + red[tid+1] + red[tid+2] + red[tid+3] + fcb[0];
}

extern "C" void kernel_launch(void* const* d_in, const int* in_sizes, int n_in,
                              void* d_out, int out_size, void* d_ws, size_t ws_size,
                              hipStream_t stream)
{
  const float* x    = (const float*)d_in[0];
  const float* wih0 = (const float*)d_in[1];
  const float* wihr = (const float*)d_in[2];
  const float* whh  = (const float*)d_in[3];
  const float* bih  = (const float*)d_in[4];
  const float* bhh  = (const float*)d_in[5];
  const float* fcw  = (const float*)d_in[6];
  const float* fcb  = (const float*)d_in[7];
  float* out = (float*)d_out;
  char* ws = (char*)d_ws;
  (void)in_sizes; (void)n_in; (void)out_size;

  if (ws_size < WS_NEEDED) return;   // ~185 MB (same budget R4-R7 ran with)

  // opt-in to 155648 B dynamic LDS (host-side, idempotent, capture-safe)
  hipFuncSetAttribute(reinterpret_cast<const void*>(lstm_main),
                      hipFuncAttributeMaxDynamicSharedMemorySize, LDS_TOTAL);

  hipMemsetAsync(ws + CNT_OFF, 0, (size_t)CNT_BYTES, stream);
  pack_kernel<<<512, 256, 0, stream>>>(wihr, whh, ws);
  lstm_main<<<256, 256, LDS_TOTAL, stream>>>(x, wih0, bih, bhh, ws);
  fc_kernel<<<1, 256, 0, stream>>>(ws, fcw, fcb, out);
}